// Round 1
// 436.976 us; speedup vs baseline: 1.8981x; 1.8981x over previous
//
#include <hip/hip_runtime.h>
#include <math.h>
#include <stdint.h>

#define NB 16
#define NS 2048
#define NT 1024
#define NE 256
#define ND 256
#define NM (NB * NT)  // 16384

typedef short sh8 __attribute__((ext_vector_type(8)));
typedef float f4v __attribute__((ext_vector_type(4)));

// ---------------- dtype helpers ----------------
static __device__ __forceinline__ float bf2f(unsigned short u) {
    union { unsigned int i; float f; } v;
    v.i = ((unsigned int)u) << 16;
    return v.f;
}
static __device__ __forceinline__ unsigned short f2bf(float f) {
    union { unsigned int i; float f; } v;
    v.f = f;
    unsigned int x = v.i;
    x += 0x7FFFu + ((x >> 16) & 1u);  // round-to-nearest-even
    return (unsigned short)(x >> 16);
}
// load 4 consecutive elements (idx multiple of 4) as float4, from fp32 or bf16 storage
static __device__ __forceinline__ float4 load4(const void* p, int isbf, long idx) {
    if (isbf) {
        const unsigned short* h = (const unsigned short*)p + idx;
        ushort4 u = *(const ushort4*)h;
        return make_float4(bf2f(u.x), bf2f(u.y), bf2f(u.z), bf2f(u.w));
    }
    const float* f = (const float*)p + idx;
    return *(const float4*)f;
}
// mask validity under 4 possible storage dtypes: 0=u8 bool, 1=i32, 2=bf16, 3=f32
static __device__ __forceinline__ int mvalid(const void* m, int kind, int b, int s) {
    long idx = (long)b * NS + s;
    switch (kind) {
        case 0:  return ((const unsigned char*)m)[idx] != 0;
        case 1:  return ((const int*)m)[idx] != 0;
        case 2:  return ((const unsigned short*)m)[idx] != 0;
        default: return ((const unsigned int*)m)[idx] != 0;
    }
}

// ---------------- dtype detector ----------------
__global__ void k_detect(const void* __restrict__ enc_raw,
                         const void* __restrict__ mask_raw,
                         int* __restrict__ flags) {
    __shared__ int cnt;
    if (threadIdx.x == 0) cnt = 0;
    __syncthreads();
    const unsigned short* h = (const unsigned short*)enc_raw;
    int local = 0;
    for (int i = threadIdx.x; i < 4096; i += 256) {
        int ex = (h[i] >> 7) & 0xFF;
        if (ex >= 97 && ex <= 157) local++;
    }
    atomicAdd(&cnt, local);
    __syncthreads();
    if (threadIdx.x == 0) {
        int isbf = (cnt >= 3700) ? 1 : 0;
        const unsigned char* mb = (const unsigned char*)mask_raw;
        int kind;
        if (mb[1] == 0x3F)                       kind = 2;
        else if (mb[3] == 0x3F && mb[1] == 0)    kind = 3;
        else if (mb[1] == 1)                     kind = 0;
        else if (mb[4] == 1 || mb[8] == 1)       kind = 1;
        else                                     kind = (mb[NS] == 1) ? 0 : 1;
        flags[0] = isbf;
        flags[1] = kind;
    }
}

// ---------------- split enc into bf16 hi/lo pair ----------------
__global__ __launch_bounds__(256) void k_split_e(const void* __restrict__ enc,
                                                 const int* __restrict__ flags,
                                                 unsigned short* __restrict__ eh,
                                                 unsigned short* __restrict__ el) {
    const int isbf = flags[0];
    const long i = ((long)blockIdx.x * 256 + threadIdx.x) * 8;
    if (isbf) {
        sh8 v = *(const sh8*)((const unsigned short*)enc + i);
        *(sh8*)(eh + i) = v;   // el never read in bf16 path
    } else {
        const float* f = (const float*)enc + i;
        sh8 hv, lv;
#pragma unroll
        for (int j = 0; j < 8; ++j) {
            float x = f[j];
            unsigned short h = f2bf(x);
            hv[j] = (short)h;
            lv[j] = (short)f2bf(x - bf2f(h));
        }
        *(sh8*)(eh + i) = hv;
        *(sh8*)(el + i) = lv;
    }
}

// ---------------- K1: qproj[m,e] = sum_d dec[m,d] * W_enc[e,d], split to bf16 hi/lo ----------------
__global__ __launch_bounds__(256) void k_q(const void* __restrict__ dec,
                                           const void* __restrict__ Wenc,
                                           const int* __restrict__ flags,
                                           unsigned short* __restrict__ qh,
                                           unsigned short* __restrict__ ql) {
    const int isbf = flags[0];
    const int tid = threadIdx.x;
    const int tx = tid & 15, ty = tid >> 4;
    const int m0 = blockIdx.x * 64, n0 = blockIdx.y * 64;
    __shared__ float As[16][68];  // [k][m]
    __shared__ float Bs[16][68];  // [k][n]
    float acc[4][4] = {};
    const int lrow = tid >> 2;
    const int lk4  = (tid & 3) << 2;
    for (int kt = 0; kt < ND; kt += 16) {
        float4 av = load4(dec,  isbf, (long)(m0 + lrow) * ND + kt + lk4);
        float4 bv = load4(Wenc, isbf, (long)(n0 + lrow) * ND + kt + lk4);
        As[lk4 + 0][lrow] = av.x; As[lk4 + 1][lrow] = av.y;
        As[lk4 + 2][lrow] = av.z; As[lk4 + 3][lrow] = av.w;
        Bs[lk4 + 0][lrow] = bv.x; Bs[lk4 + 1][lrow] = bv.y;
        Bs[lk4 + 2][lrow] = bv.z; Bs[lk4 + 3][lrow] = bv.w;
        __syncthreads();
#pragma unroll
        for (int k = 0; k < 16; ++k) {
            float4 a = *(const float4*)&As[k][ty << 2];
            float4 b = *(const float4*)&Bs[k][tx << 2];
            acc[0][0] = fmaf(a.x, b.x, acc[0][0]); acc[0][1] = fmaf(a.x, b.y, acc[0][1]);
            acc[0][2] = fmaf(a.x, b.z, acc[0][2]); acc[0][3] = fmaf(a.x, b.w, acc[0][3]);
            acc[1][0] = fmaf(a.y, b.x, acc[1][0]); acc[1][1] = fmaf(a.y, b.y, acc[1][1]);
            acc[1][2] = fmaf(a.y, b.z, acc[1][2]); acc[1][3] = fmaf(a.y, b.w, acc[1][3]);
            acc[2][0] = fmaf(a.z, b.x, acc[2][0]); acc[2][1] = fmaf(a.z, b.y, acc[2][1]);
            acc[2][2] = fmaf(a.z, b.z, acc[2][2]); acc[2][3] = fmaf(a.z, b.w, acc[2][3]);
            acc[3][0] = fmaf(a.w, b.x, acc[3][0]); acc[3][1] = fmaf(a.w, b.y, acc[3][1]);
            acc[3][2] = fmaf(a.w, b.z, acc[3][2]); acc[3][3] = fmaf(a.w, b.w, acc[3][3]);
        }
        __syncthreads();
    }
#pragma unroll
    for (int i = 0; i < 4; ++i) {
        long base = (long)(m0 + (ty << 2) + i) * NE + n0 + (tx << 2);
        ushort4 hv, lv;
        {
            float f0 = acc[i][0]; unsigned short h = f2bf(f0); hv.x = h; lv.x = f2bf(f0 - bf2f(h));
            float f1 = acc[i][1]; h = f2bf(f1); hv.y = h; lv.y = f2bf(f1 - bf2f(h));
            float f2 = acc[i][2]; h = f2bf(f2); hv.z = h; lv.z = f2bf(f2 - bf2f(h));
            float f3 = acc[i][3]; h = f2bf(f3); hv.w = h; lv.w = f2bf(f3 - bf2f(h));
        }
        *(ushort4*)&qh[base] = hv;
        *(ushort4*)&ql[base] = lv;
    }
}

// ---------------- K2: MFMA flash attention ----------------
// Block: (b, 32 t-rows), 4 waves. Scores via swapped QK^T (C^T[s][t]) with bf16x3
// compensation: s = qh*eh + ql*eh + qh*el (fp32 accum). PV via bf16 MFMA with
// transposed-V LDS copy. Online softmax bookkeeping in LDS.
__global__ __launch_bounds__(256, 2) void k_attn(
    const unsigned short* __restrict__ qh, const unsigned short* __restrict__ ql,
    const unsigned short* __restrict__ eh, const unsigned short* __restrict__ el,
    const void* __restrict__ mask, const int* __restrict__ flags,
    float* __restrict__ ctx)
{
    const int isbf  = flags[0];
    const int mkind = flags[1];
    const int b  = blockIdx.y;
    const int t0 = blockIdx.x * 32;
    const int tid  = threadIdx.x;
    const int lane = tid & 63;
    const int wid  = tid >> 6;
    const int th = wid & 1;      // t-half (scores C cols, PV C rows)
    const int sh = wid >> 1;     // s-half (scores) / e-half (PV)
    const int lr = lane & 15;
    const int lg = lane >> 4;

    __shared__ __align__(16) unsigned short EHR[32][264];  // eh row-major [s][e] (scores A)
    __shared__ __align__(16) unsigned short ELR[32][264];  // el row-major [s][e] (scores A)
    __shared__ __align__(16) unsigned short VTs[256][40];  // eh transposed [e][s] (PV B)
    __shared__ __align__(16) unsigned short PBs[32][32];   // P bf16 [t][s] (PV A)
    __shared__ float hm[2][32];   // per-s-half row max
    __shared__ float hs[2][32];   // per-s-half row sum
    __shared__ float Ml[32];      // running max
    __shared__ float Ll[32];      // running denom
    __shared__ float Al[32];      // rescale factor this tile

    // ---- Q fragments, resident in registers for the whole kernel ----
    // B-frag layout: lane holds Q[t = t0+th*16+lr][e = k8*32 + lg*8 + j]
    sh8 qhf[8], qlf[8];
    {
        const unsigned short* qp  = qh + ((long)b * NT + t0 + th * 16 + lr) * NE + lg * 8;
        const unsigned short* qp2 = ql + ((long)b * NT + t0 + th * 16 + lr) * NE + lg * 8;
#pragma unroll
        for (int k8 = 0; k8 < 8; ++k8) {
            qhf[k8] = *(const sh8*)(qp  + k8 * 32);
            qlf[k8] = *(const sh8*)(qp2 + k8 * 32);
        }
    }

    f4v O[8];
#pragma unroll
    for (int et = 0; et < 8; ++et) O[et] = (f4v){0.f, 0.f, 0.f, 0.f};

    if (tid < 32) { Ml[tid] = -INFINITY; Ll[tid] = 0.f; }

    const int ss = tid >> 3;          // staging: source row 0..31
    const int ee = (tid & 7) * 8;     // staging: col base

    for (int s0 = 0; s0 < NS; s0 += 32) {
        if (!mvalid(mask, mkind, b, s0)) break;   // prefix mask
        __syncthreads();   // B1: prev PV done before overwriting tiles
        // ---- stage enc tile: row-major hi/lo + transposed hi ----
        {
            const unsigned short* eg = eh + ((long)b * NS + s0 + ss) * NE;
#pragma unroll
            for (int c = 0; c < 4; ++c) {
                int e = ee + c * 64;
                sh8 v = *(const sh8*)(eg + e);
                *(sh8*)&EHR[ss][e] = v;
#pragma unroll
                for (int j = 0; j < 8; ++j) VTs[e + j][ss] = (unsigned short)v[j];
            }
            if (!isbf) {
                const unsigned short* eg2 = el + ((long)b * NS + s0 + ss) * NE;
#pragma unroll
                for (int c = 0; c < 4; ++c) {
                    int e = ee + c * 64;
                    *(sh8*)&ELR[ss][e] = *(const sh8*)(eg2 + e);
                }
            }
        }
        __syncthreads();   // B2: tiles visible
        // ---- scores: C^T[s][t] quadrant per wave, bf16x3 compensated ----
        f4v cacc = (f4v){0.f, 0.f, 0.f, 0.f};
        {
            const unsigned short* ep = &EHR[sh * 16 + lr][lg * 8];
            const unsigned short* lp = &ELR[sh * 16 + lr][lg * 8];
            if (isbf) {
#pragma unroll
                for (int k8 = 0; k8 < 8; ++k8) {
                    sh8 ea = *(const sh8*)(ep + k8 * 32);
                    cacc = __builtin_amdgcn_mfma_f32_16x16x32_bf16(ea, qhf[k8], cacc, 0, 0, 0);
                    cacc = __builtin_amdgcn_mfma_f32_16x16x32_bf16(ea, qlf[k8], cacc, 0, 0, 0);
                }
            } else {
#pragma unroll
                for (int k8 = 0; k8 < 8; ++k8) {
                    sh8 ea = *(const sh8*)(ep + k8 * 32);
                    sh8 eb = *(const sh8*)(lp + k8 * 32);
                    cacc = __builtin_amdgcn_mfma_f32_16x16x32_bf16(ea, qhf[k8], cacc, 0, 0, 0);
                    cacc = __builtin_amdgcn_mfma_f32_16x16x32_bf16(ea, qlf[k8], cacc, 0, 0, 0);
                    cacc = __builtin_amdgcn_mfma_f32_16x16x32_bf16(eb, qhf[k8], cacc, 0, 0, 0);
                }
            }
        }
        // ---- online softmax ----
        float sc[4];
#pragma unroll
        for (int r = 0; r < 4; ++r) {
            int sl = sh * 16 + lg * 4 + r;
            sc[r] = mvalid(mask, mkind, b, s0 + sl) ? cacc[r] : -INFINITY;
        }
        float m4 = fmaxf(fmaxf(sc[0], sc[1]), fmaxf(sc[2], sc[3]));
        m4 = fmaxf(m4, __shfl_xor(m4, 16));
        m4 = fmaxf(m4, __shfl_xor(m4, 32));
        if (lane < 16) hm[sh][th * 16 + lane] = m4;
        __syncthreads();   // B3: half-maxes visible
        const int tl = th * 16 + lr;
        float mOld = Ml[tl];
        float newM = fmaxf(mOld, fmaxf(hm[0][tl], hm[1][tl]));
        float alpha = __expf(mOld - newM);   // exp(-inf)=0 on first tile; O is 0 anyway
        float p[4], ps = 0.f;
#pragma unroll
        for (int r = 0; r < 4; ++r) {
            p[r] = (sc[r] == -INFINITY) ? 0.f : __expf(sc[r] - newM);
            ps += p[r];
        }
        ps += __shfl_xor(ps, 16);
        ps += __shfl_xor(ps, 32);
        if (lane < 16) hs[sh][th * 16 + lane] = ps;
        if (wid < 2 && lane < 16) Al[th * 16 + lane] = alpha;  // sh==0 waves cover all t
        {
            ushort4 pw;
            pw.x = f2bf(p[0]); pw.y = f2bf(p[1]); pw.z = f2bf(p[2]); pw.w = f2bf(p[3]);
            *(ushort4*)&PBs[tl][sh * 16 + lg * 4] = pw;
        }
        __syncthreads();   // B4: P, sums, alpha visible
        if (wid < 2 && lane < 16) {
            Ll[tl] = Ll[tl] * alpha + hs[0][tl] + hs[1][tl];
            Ml[tl] = newM;
        }
        // ---- PV: O (rows t, cols e) rescale + accumulate ----
        f4v av = *(const f4v*)&Al[th * 16 + lg * 4];
#pragma unroll
        for (int et = 0; et < 8; ++et) O[et] *= av;
        sh8 pf = *(const sh8*)&PBs[th * 16 + lr][lg * 8];
#pragma unroll
        for (int et = 0; et < 8; ++et) {
            sh8 vf = *(const sh8*)&VTs[sh * 128 + et * 16 + lr][lg * 8];
            O[et] = __builtin_amdgcn_mfma_f32_16x16x32_bf16(pf, vf, O[et], 0, 0, 0);
        }
    }
    // ---- epilogue: normalize and store ----
    __syncthreads();
    f4v lv = *(const f4v*)&Ll[th * 16 + lg * 4];
    f4v inv;
#pragma unroll
    for (int r = 0; r < 4; ++r) inv[r] = 1.0f / lv[r];
#pragma unroll
    for (int et = 0; et < 8; ++et) {
        f4v ov = O[et] * inv;
        long rbase = ((long)b * NT + t0 + th * 16 + lg * 4) * NE + sh * 128 + et * 16 + lr;
#pragma unroll
        for (int r = 0; r < 4; ++r)
            ctx[rbase + (long)r * NE] = ov[r];
    }
}

// ---------------- K3: out = tanh([ctx | dec] @ W_fin) ----------------
__global__ __launch_bounds__(256) void k_final(const float* __restrict__ ctx,
                                               const void* __restrict__ dec,
                                               const void* __restrict__ Wfin,
                                               const int* __restrict__ flags,
                                               void* __restrict__ out) {
    const int isbf = flags[0];
    const int tid = threadIdx.x;
    const int tx = tid & 15, ty = tid >> 4;
    const int m0 = blockIdx.x * 64, n0 = blockIdx.y * 64;
    __shared__ float As[16][68];
    __shared__ float Bs[16][68];
    float acc[4][4] = {};
    const int lrow = tid >> 2;
    const int lk4  = (tid & 3) << 2;
    const int lkb  = tid >> 4;
    const int ln4  = (tid & 15) << 2;
    for (int kt = 0; kt < NE + ND; kt += 16) {
        float4 av;
        if (kt < NE) {
            av = *(const float4*)&ctx[(long)(m0 + lrow) * NE + kt + lk4];
        } else {
            av = load4(dec, isbf, (long)(m0 + lrow) * ND + (kt - NE) + lk4);
        }
        float4 bv = load4(Wfin, isbf, (long)(kt + lkb) * ND + n0 + ln4);
        As[lk4 + 0][lrow] = av.x; As[lk4 + 1][lrow] = av.y;
        As[lk4 + 2][lrow] = av.z; As[lk4 + 3][lrow] = av.w;
        *(float4*)&Bs[lkb][ln4] = bv;
        __syncthreads();
#pragma unroll
        for (int k = 0; k < 16; ++k) {
            float4 a = *(const float4*)&As[k][ty << 2];
            float4 b = *(const float4*)&Bs[k][tx << 2];
            acc[0][0] = fmaf(a.x, b.x, acc[0][0]); acc[0][1] = fmaf(a.x, b.y, acc[0][1]);
            acc[0][2] = fmaf(a.x, b.z, acc[0][2]); acc[0][3] = fmaf(a.x, b.w, acc[0][3]);
            acc[1][0] = fmaf(a.y, b.x, acc[1][0]); acc[1][1] = fmaf(a.y, b.y, acc[1][1]);
            acc[1][2] = fmaf(a.y, b.z, acc[1][2]); acc[1][3] = fmaf(a.y, b.w, acc[1][3]);
            acc[2][0] = fmaf(a.z, b.x, acc[2][0]); acc[2][1] = fmaf(a.z, b.y, acc[2][1]);
            acc[2][2] = fmaf(a.z, b.z, acc[2][2]); acc[2][3] = fmaf(a.z, b.w, acc[2][3]);
            acc[3][0] = fmaf(a.w, b.x, acc[3][0]); acc[3][1] = fmaf(a.w, b.y, acc[3][1]);
            acc[3][2] = fmaf(a.w, b.z, acc[3][2]); acc[3][3] = fmaf(a.w, b.w, acc[3][3]);
        }
        __syncthreads();
    }
    if (isbf) {
        unsigned short* o = (unsigned short*)out;
#pragma unroll
        for (int i = 0; i < 4; ++i) {
            long base = (long)(m0 + (ty << 2) + i) * ND + n0 + (tx << 2);
            ushort4 r;
            r.x = f2bf(tanhf(acc[i][0])); r.y = f2bf(tanhf(acc[i][1]));
            r.z = f2bf(tanhf(acc[i][2])); r.w = f2bf(tanhf(acc[i][3]));
            *(ushort4*)&o[base] = r;
        }
    } else {
        float* o = (float*)out;
#pragma unroll
        for (int i = 0; i < 4; ++i) {
            long base = (long)(m0 + (ty << 2) + i) * ND + n0 + (tx << 2);
            float4 r = make_float4(tanhf(acc[i][0]), tanhf(acc[i][1]),
                                   tanhf(acc[i][2]), tanhf(acc[i][3]));
            *(float4*)&o[base] = r;
        }
    }
}

extern "C" void kernel_launch(void* const* d_in, const int* in_sizes, int n_in,
                              void* d_out, int out_size, void* d_ws, size_t ws_size,
                              hipStream_t stream) {
    const void* enc  = d_in[0];  // (B,S,E)
    const void* dec  = d_in[1];  // (B,T,D)
    const void* mask = d_in[2];  // (B,S) bool
    const void* Wenc = d_in[3];  // (E,D)
    const void* Wfin = d_in[4];  // (E+D,D)

    unsigned short* ehb = (unsigned short*)d_ws;              // 16.8 MB
    unsigned short* elb = ehb + (size_t)NB * NS * NE;         // 16.8 MB
    unsigned short* qhb = elb + (size_t)NB * NS * NE;         // 8.4 MB
    unsigned short* qlb = qhb + (size_t)NM * NE;              // 8.4 MB
    float* ctx  = (float*)(qlb + (size_t)NM * NE);            // 16.8 MB
    int*   flags = (int*)(ctx + (size_t)NM * NE);

    k_detect<<<1, 256, 0, stream>>>(enc, mask, flags);
    k_split_e<<<(NB * NS * NE) / (256 * 8), 256, 0, stream>>>(enc, flags, ehb, elb);
    k_q<<<dim3(NM / 64, NE / 64), 256, 0, stream>>>(dec, Wenc, flags, qhb, qlb);
    k_attn<<<dim3(NT / 32, NB), 256, 0, stream>>>(qhb, qlb, ehb, elb, mask, flags, ctx);
    k_final<<<dim3(NM / 64, ND / 64), 256, 0, stream>>>(ctx, dec, Wfin, flags, d_out);
}

// Round 2
// 315.692 us; speedup vs baseline: 2.6274x; 1.3842x over previous
//
#include <hip/hip_runtime.h>
#include <math.h>
#include <stdint.h>

#define NB 16
#define NS 2048
#define NT 1024
#define NE 256
#define ND 256
#define NM (NB * NT)  // 16384

typedef short sh8 __attribute__((ext_vector_type(8)));
typedef float f4v __attribute__((ext_vector_type(4)));

// ---------------- dtype helpers ----------------
static __device__ __forceinline__ float bf2f(unsigned short u) {
    union { unsigned int i; float f; } v;
    v.i = ((unsigned int)u) << 16;
    return v.f;
}
static __device__ __forceinline__ unsigned short f2bf(float f) {
    union { unsigned int i; float f; } v;
    v.f = f;
    unsigned int x = v.i;
    x += 0x7FFFu + ((x >> 16) & 1u);  // round-to-nearest-even
    return (unsigned short)(x >> 16);
}
static __device__ __forceinline__ float4 load4(const void* p, int isbf, long idx) {
    if (isbf) {
        const unsigned short* h = (const unsigned short*)p + idx;
        ushort4 u = *(const ushort4*)h;
        return make_float4(bf2f(u.x), bf2f(u.y), bf2f(u.z), bf2f(u.w));
    }
    const float* f = (const float*)p + idx;
    return *(const float4*)f;
}
static __device__ __forceinline__ int mvalid(const void* m, int kind, int b, int s) {
    long idx = (long)b * NS + s;
    switch (kind) {
        case 0:  return ((const unsigned char*)m)[idx] != 0;
        case 1:  return ((const int*)m)[idx] != 0;
        case 2:  return ((const unsigned short*)m)[idx] != 0;
        default: return ((const unsigned int*)m)[idx] != 0;
    }
}

// ---------------- dtype detector ----------------
__global__ void k_detect(const void* __restrict__ enc_raw,
                         const void* __restrict__ mask_raw,
                         int* __restrict__ flags) {
    __shared__ int cnt;
    if (threadIdx.x == 0) cnt = 0;
    __syncthreads();
    const unsigned short* h = (const unsigned short*)enc_raw;
    int local = 0;
    for (int i = threadIdx.x; i < 4096; i += 256) {
        int ex = (h[i] >> 7) & 0xFF;
        if (ex >= 97 && ex <= 157) local++;
    }
    atomicAdd(&cnt, local);
    __syncthreads();
    if (threadIdx.x == 0) {
        int isbf = (cnt >= 3700) ? 1 : 0;
        const unsigned char* mb = (const unsigned char*)mask_raw;
        int kind;
        if (mb[1] == 0x3F)                       kind = 2;
        else if (mb[3] == 0x3F && mb[1] == 0)    kind = 3;
        else if (mb[1] == 1)                     kind = 0;
        else if (mb[4] == 1 || mb[8] == 1)       kind = 1;
        else                                     kind = (mb[NS] == 1) ? 0 : 1;
        flags[0] = isbf;
        flags[1] = kind;
    }
}

// ---------------- split enc into bf16 hi/lo pair ----------------
__global__ __launch_bounds__(256) void k_split_e(const void* __restrict__ enc,
                                                 const int* __restrict__ flags,
                                                 unsigned short* __restrict__ eh,
                                                 unsigned short* __restrict__ el) {
    const int isbf = flags[0];
    const long i = ((long)blockIdx.x * 256 + threadIdx.x) * 8;
    if (isbf) {
        sh8 v = *(const sh8*)((const unsigned short*)enc + i);
        *(sh8*)(eh + i) = v;
    } else {
        const float* f = (const float*)enc + i;
        sh8 hv, lv;
#pragma unroll
        for (int j = 0; j < 8; ++j) {
            float x = f[j];
            unsigned short h = f2bf(x);
            hv[j] = (short)h;
            lv[j] = (short)f2bf(x - bf2f(h));
        }
        *(sh8*)(eh + i) = hv;
        *(sh8*)(el + i) = lv;
    }
}

// ---------------- K1: qproj = dec @ W_enc^T, split to bf16 hi/lo ----------------
__global__ __launch_bounds__(256) void k_q(const void* __restrict__ dec,
                                           const void* __restrict__ Wenc,
                                           const int* __restrict__ flags,
                                           unsigned short* __restrict__ qh,
                                           unsigned short* __restrict__ ql) {
    const int isbf = flags[0];
    const int tid = threadIdx.x;
    const int tx = tid & 15, ty = tid >> 4;
    const int m0 = blockIdx.x * 64, n0 = blockIdx.y * 64;
    __shared__ float As[16][68];
    __shared__ float Bs[16][68];
    float acc[4][4] = {};
    const int lrow = tid >> 2;
    const int lk4  = (tid & 3) << 2;
    for (int kt = 0; kt < ND; kt += 16) {
        float4 av = load4(dec,  isbf, (long)(m0 + lrow) * ND + kt + lk4);
        float4 bv = load4(Wenc, isbf, (long)(n0 + lrow) * ND + kt + lk4);
        As[lk4 + 0][lrow] = av.x; As[lk4 + 1][lrow] = av.y;
        As[lk4 + 2][lrow] = av.z; As[lk4 + 3][lrow] = av.w;
        Bs[lk4 + 0][lrow] = bv.x; Bs[lk4 + 1][lrow] = bv.y;
        Bs[lk4 + 2][lrow] = bv.z; Bs[lk4 + 3][lrow] = bv.w;
        __syncthreads();
#pragma unroll
        for (int k = 0; k < 16; ++k) {
            float4 a = *(const float4*)&As[k][ty << 2];
            float4 b = *(const float4*)&Bs[k][tx << 2];
            acc[0][0] = fmaf(a.x, b.x, acc[0][0]); acc[0][1] = fmaf(a.x, b.y, acc[0][1]);
            acc[0][2] = fmaf(a.x, b.z, acc[0][2]); acc[0][3] = fmaf(a.x, b.w, acc[0][3]);
            acc[1][0] = fmaf(a.y, b.x, acc[1][0]); acc[1][1] = fmaf(a.y, b.y, acc[1][1]);
            acc[1][2] = fmaf(a.y, b.z, acc[1][2]); acc[1][3] = fmaf(a.y, b.w, acc[1][3]);
            acc[2][0] = fmaf(a.z, b.x, acc[2][0]); acc[2][1] = fmaf(a.z, b.y, acc[2][1]);
            acc[2][2] = fmaf(a.z, b.z, acc[2][2]); acc[2][3] = fmaf(a.z, b.w, acc[2][3]);
            acc[3][0] = fmaf(a.w, b.x, acc[3][0]); acc[3][1] = fmaf(a.w, b.y, acc[3][1]);
            acc[3][2] = fmaf(a.w, b.z, acc[3][2]); acc[3][3] = fmaf(a.w, b.w, acc[3][3]);
        }
        __syncthreads();
    }
#pragma unroll
    for (int i = 0; i < 4; ++i) {
        long base = (long)(m0 + (ty << 2) + i) * NE + n0 + (tx << 2);
        ushort4 hv, lv;
        {
            float f0 = acc[i][0]; unsigned short h = f2bf(f0); hv.x = h; lv.x = f2bf(f0 - bf2f(h));
            float f1 = acc[i][1]; h = f2bf(f1); hv.y = h; lv.y = f2bf(f1 - bf2f(h));
            float f2 = acc[i][2]; h = f2bf(f2); hv.z = h; lv.z = f2bf(f2 - bf2f(h));
            float f3 = acc[i][3]; h = f2bf(f3); hv.w = h; lv.w = f2bf(f3 - bf2f(h));
        }
        *(ushort4*)&qh[base] = hv;
        *(ushort4*)&ql[base] = lv;
    }
}

// ---------------- K2: MFMA flash attention, 2 barriers/tile ----------------
// Waves (th,sh). Scores C^T[s][t] via bf16x3. Per-half softmax published once;
// running (M,L) per t-row kept redundantly in registers. VT double-buffered +
// swizzled; staging loads issued before PV (latency hidden under MFMA).
// grid.z = parts (s-range split); parts>1 writes unnormalized O + (M,L).
__global__ __launch_bounds__(256, 2) void k_attn(
    const unsigned short* __restrict__ qh, const unsigned short* __restrict__ ql,
    const unsigned short* __restrict__ eh, const unsigned short* __restrict__ el,
    const void* __restrict__ mask, const int* __restrict__ flags,
    float* __restrict__ ctx, float* __restrict__ Mp, float* __restrict__ Lp)
{
    const int isbf  = flags[0];
    const int mkind = flags[1];
    const int b  = blockIdx.y;
    const int t0 = blockIdx.x * 32;
    const int part = blockIdx.z, nparts = gridDim.z;
    const int tid  = threadIdx.x;
    const int lane = tid & 63;
    const int wid  = tid >> 6;
    const int th = wid & 1;      // t-half
    const int sh = wid >> 1;     // s-half (scores) / e-half (PV)
    const int lr = lane & 15;
    const int lg = lane >> 4;

    __shared__ __align__(16) unsigned short EHR[32][264];      // eh row-major [s][e]
    __shared__ __align__(16) unsigned short ELR[32][264];      // el row-major [s][e]
    __shared__ __align__(16) unsigned short VT[2][256][40];    // eh transposed [e][s^swz], dbuf
    __shared__ __align__(16) float PBs[32][36];                // P f32 [t][s] (local-max scaled)
    __shared__ float hm[2][32];                                // per-half row max
    __shared__ float hs[2][32];                                // per-half row sum
    __shared__ int s_len;

    // ---- mask -> length (prefix mask) ----
    if (tid == 0) s_len = 0;
    __syncthreads();
    {
        int c = 0;
#pragma unroll
        for (int j = 0; j < 8; ++j) c += mvalid(mask, mkind, b, tid * 8 + j);
        atomicAdd(&s_len, c);
    }
    __syncthreads();
    const int len  = s_len;
    const int s_lo = part * (NS / nparts);
    const int s_hi = min(s_lo + NS / nparts, len);
    const int ntiles = (s_hi > s_lo) ? ((s_hi - s_lo + 31) >> 5) : 0;
    const long mrow = (long)part * NM + (long)b * NT + t0;
    if (ntiles == 0) {
        if (nparts > 1 && tid < 32) { Mp[mrow + tid] = -INFINITY; Lp[mrow + tid] = 0.f; }
        return;
    }

    // ---- Q fragments resident in registers ----
    sh8 qhf[8], qlf[8];
    {
        const unsigned short* qp  = qh + ((long)b * NT + t0 + th * 16 + lr) * NE + lg * 8;
        const unsigned short* qp2 = ql + ((long)b * NT + t0 + th * 16 + lr) * NE + lg * 8;
#pragma unroll
        for (int k8 = 0; k8 < 8; ++k8) {
            qhf[k8] = *(const sh8*)(qp  + k8 * 32);
            qlf[k8] = *(const sh8*)(qp2 + k8 * 32);
        }
    }

    f4v O[8];
#pragma unroll
    for (int et = 0; et < 8; ++et) O[et] = (f4v){0.f, 0.f, 0.f, 0.f};
    float Mreg4[4], L4[4], MregP = -INFINITY;
#pragma unroll
    for (int r = 0; r < 4; ++r) { Mreg4[r] = -INFINITY; L4[r] = 0.f; }

    const int ss = tid >> 3;        // staging source row 0..31
    const int ee = (tid & 7) * 8;   // staging col base
    const int swzw = ((tid & 7) & 3) << 3;  // == ((e0>>3)&3)<<3 for this lane's chunks

    sh8 rh[4], rl[4];
    // prologue: stage tile 0 into buffer 0
    {
        const unsigned short* eg = eh + ((long)b * NS + s_lo + ss) * NE;
#pragma unroll
        for (int c = 0; c < 4; ++c) rh[c] = *(const sh8*)(eg + ee + c * 64);
        if (!isbf) {
            const unsigned short* eg2 = el + ((long)b * NS + s_lo + ss) * NE;
#pragma unroll
            for (int c = 0; c < 4; ++c) rl[c] = *(const sh8*)(eg2 + ee + c * 64);
        }
#pragma unroll
        for (int c = 0; c < 4; ++c) {
            const int e0 = ee + c * 64;
            *(sh8*)&EHR[ss][e0] = rh[c];
            if (!isbf) *(sh8*)&ELR[ss][e0] = rl[c];
            const int cs = ss ^ swzw;
#pragma unroll
            for (int j = 0; j < 8; ++j) VT[0][e0 + j][cs] = (unsigned short)rh[c][j];
        }
    }
    int cur = 0;

    for (int it = 0; it < ntiles; ++it) {
        const int s0 = s_lo + it * 32;
        __syncthreads();   // B2: stage(it) visible
        // ---- scores ----
        f4v cacc = (f4v){0.f, 0.f, 0.f, 0.f};
        {
            const unsigned short* ep = &EHR[sh * 16 + lr][lg * 8];
            const unsigned short* lp = &ELR[sh * 16 + lr][lg * 8];
            if (isbf) {
#pragma unroll
                for (int k8 = 0; k8 < 8; ++k8) {
                    sh8 ea = *(const sh8*)(ep + k8 * 32);
                    cacc = __builtin_amdgcn_mfma_f32_16x16x32_bf16(ea, qhf[k8], cacc, 0, 0, 0);
                    cacc = __builtin_amdgcn_mfma_f32_16x16x32_bf16(ea, qlf[k8], cacc, 0, 0, 0);
                }
            } else {
#pragma unroll
                for (int k8 = 0; k8 < 8; ++k8) {
                    sh8 ea = *(const sh8*)(ep + k8 * 32);
                    sh8 eb = *(const sh8*)(lp + k8 * 32);
                    cacc = __builtin_amdgcn_mfma_f32_16x16x32_bf16(ea, qhf[k8], cacc, 0, 0, 0);
                    cacc = __builtin_amdgcn_mfma_f32_16x16x32_bf16(ea, qlf[k8], cacc, 0, 0, 0);
                    cacc = __builtin_amdgcn_mfma_f32_16x16x32_bf16(eb, qhf[k8], cacc, 0, 0, 0);
                }
            }
        }
        // ---- per-half softmax publish ----
        float sc[4];
#pragma unroll
        for (int r = 0; r < 4; ++r) {
            int sl = sh * 16 + lg * 4 + r;
            sc[r] = (s0 + sl < len) ? cacc[r] : -INFINITY;
        }
        float m4 = fmaxf(fmaxf(sc[0], sc[1]), fmaxf(sc[2], sc[3]));
        m4 = fmaxf(m4, __shfl_xor(m4, 16));
        m4 = fmaxf(m4, __shfl_xor(m4, 32));
        float p[4], ps = 0.f;
#pragma unroll
        for (int r = 0; r < 4; ++r) {
            p[r] = (sc[r] == -INFINITY) ? 0.f : __expf(sc[r] - m4);
            ps += p[r];
        }
        ps += __shfl_xor(ps, 16);
        ps += __shfl_xor(ps, 32);
        if (lane < 16) { hm[sh][th * 16 + lane] = m4; hs[sh][th * 16 + lane] = ps; }
        *(float4*)&PBs[th * 16 + lr][sh * 16 + lg * 4] = make_float4(p[0], p[1], p[2], p[3]);
        __syncthreads();   // B5: publish visible (also: all EHR/ELR reads done)
        // ---- register (M,L) update ----
        float f0, f1, al[4];
        {
            const int tP = th * 16 + lr;
            float h0 = hm[0][tP], h1 = hm[1][tP];
            float Mn = fmaxf(MregP, fmaxf(h0, h1));
            f0 = __expf(h0 - Mn);   // exp(-inf - finite) = 0
            f1 = __expf(h1 - Mn);
            MregP = Mn;
        }
#pragma unroll
        for (int r = 0; r < 4; ++r) {
            const int t4 = th * 16 + lg * 4 + r;
            float g0 = hm[0][t4], g1 = hm[1][t4];
            float Mn = fmaxf(Mreg4[r], fmaxf(g0, g1));
            al[r] = __expf(Mreg4[r] - Mn);
            L4[r] = L4[r] * al[r] + hs[0][t4] * __expf(g0 - Mn) + hs[1][t4] * __expf(g1 - Mn);
            Mreg4[r] = Mn;
        }
        // ---- issue next-tile global loads (latency hidden under PV) ----
        const int more = (it + 1 < ntiles);
        if (more) {
            const unsigned short* eg = eh + ((long)b * NS + s0 + 32 + ss) * NE;
#pragma unroll
            for (int c = 0; c < 4; ++c) rh[c] = *(const sh8*)(eg + ee + c * 64);
            if (!isbf) {
                const unsigned short* eg2 = el + ((long)b * NS + s0 + 32 + ss) * NE;
#pragma unroll
                for (int c = 0; c < 4; ++c) rl[c] = *(const sh8*)(eg2 + ee + c * 64);
            }
        }
        // ---- PV ----
        {
            const float fsc = (lg < 2) ? f0 : f1;
            f4v pA = *(const f4v*)&PBs[th * 16 + lr][lg * 8];
            f4v pB = *(const f4v*)&PBs[th * 16 + lr][lg * 8 + 4];
            sh8 pf;
#pragma unroll
            for (int j = 0; j < 4; ++j) {
                pf[j]     = (short)f2bf(pA[j] * fsc);
                pf[4 + j] = (short)f2bf(pB[j] * fsc);
            }
            f4v alv = (f4v){al[0], al[1], al[2], al[3]};
#pragma unroll
            for (int et = 0; et < 8; ++et) O[et] *= alv;
#pragma unroll
            for (int et = 0; et < 8; ++et) {
                const int row = sh * 128 + et * 16 + lr;
                sh8 vf = *(const sh8*)&VT[cur][row][(lg ^ ((row >> 3) & 3)) * 8];
                O[et] = __builtin_amdgcn_mfma_f32_16x16x32_bf16(pf, vf, O[et], 0, 0, 0);
            }
        }
        // ---- write staged regs -> LDS (other buffer) ----
        if (more) {
#pragma unroll
            for (int c = 0; c < 4; ++c) {
                const int e0 = ee + c * 64;
                *(sh8*)&EHR[ss][e0] = rh[c];
                if (!isbf) *(sh8*)&ELR[ss][e0] = rl[c];
                const int cs = ss ^ swzw;
#pragma unroll
                for (int j = 0; j < 8; ++j) VT[cur ^ 1][e0 + j][cs] = (unsigned short)rh[c][j];
            }
            cur ^= 1;
        }
    }
    // ---- epilogue ----
    if (nparts == 1) {
        f4v inv;
#pragma unroll
        for (int r = 0; r < 4; ++r) inv[r] = 1.0f / L4[r];
#pragma unroll
        for (int et = 0; et < 8; ++et) {
            f4v ov = O[et] * inv;
            long rbase = ((long)b * NT + t0 + th * 16 + lg * 4) * NE + sh * 128 + et * 16 + lr;
#pragma unroll
            for (int r = 0; r < 4; ++r)
                ctx[rbase + (long)r * NE] = ov[r];
        }
    } else {
        float* op = ctx + (long)part * NM * NE;
#pragma unroll
        for (int et = 0; et < 8; ++et) {
            long rbase = ((long)b * NT + t0 + th * 16 + lg * 4) * NE + sh * 128 + et * 16 + lr;
#pragma unroll
            for (int r = 0; r < 4; ++r)
                op[rbase + (long)r * NE] = O[et][r];
        }
        if (sh == 0 && lr == 0) {
#pragma unroll
            for (int r = 0; r < 4; ++r) {
                Mp[mrow + th * 16 + lg * 4 + r] = Mreg4[r];
                Lp[mrow + th * 16 + lg * 4 + r] = L4[r];
            }
        }
    }
}

// ---------------- combine split-s partials ----------------
__global__ __launch_bounds__(256) void k_comb(float* __restrict__ ctx,
                                              const float* __restrict__ Mp,
                                              const float* __restrict__ Lp,
                                              int nparts) {
    const long m = (long)blockIdx.x * 8 + (threadIdx.x >> 5);
    const int  e0 = (threadIdx.x & 31) * 8;
    float Mv[4], Lv[4];
    float M = -INFINITY;
    for (int p = 0; p < nparts; ++p) {
        Mv[p] = Mp[(long)p * NM + m];
        Lv[p] = Lp[(long)p * NM + m];
        if (Lv[p] > 0.f) M = fmaxf(M, Mv[p]);
    }
    float L = 0.f, w[4];
    for (int p = 0; p < nparts; ++p) {
        w[p] = (Lv[p] > 0.f) ? __expf(Mv[p] - M) : 0.f;
        L += Lv[p] * w[p];
    }
    float o[8] = {};
    for (int p = 0; p < nparts; ++p) {
        if (w[p] > 0.f) {
            const float* src = ctx + (long)p * NM * NE + m * NE + e0;
            f4v a = *(const f4v*)src;
            f4v c = *(const f4v*)(src + 4);
#pragma unroll
            for (int j = 0; j < 4; ++j) { o[j] += a[j] * w[p]; o[4 + j] += c[j] * w[p]; }
        }
    }
    const float inv = 1.0f / L;
    float* dst = ctx + m * NE + e0;
    f4v r0, r1;
#pragma unroll
    for (int j = 0; j < 4; ++j) { r0[j] = o[j] * inv; r1[j] = o[4 + j] * inv; }
    *(f4v*)dst = r0;
    *(f4v*)(dst + 4) = r1;
}

// ---------------- K3: out = tanh([ctx | dec] @ W_fin) ----------------
__global__ __launch_bounds__(256) void k_final(const float* __restrict__ ctx,
                                               const void* __restrict__ dec,
                                               const void* __restrict__ Wfin,
                                               const int* __restrict__ flags,
                                               void* __restrict__ out) {
    const int isbf = flags[0];
    const int tid = threadIdx.x;
    const int tx = tid & 15, ty = tid >> 4;
    const int m0 = blockIdx.x * 64, n0 = blockIdx.y * 64;
    __shared__ float As[16][68];
    __shared__ float Bs[16][68];
    float acc[4][4] = {};
    const int lrow = tid >> 2;
    const int lk4  = (tid & 3) << 2;
    const int lkb  = tid >> 4;
    const int ln4  = (tid & 15) << 2;
    for (int kt = 0; kt < NE + ND; kt += 16) {
        float4 av;
        if (kt < NE) {
            av = *(const float4*)&ctx[(long)(m0 + lrow) * NE + kt + lk4];
        } else {
            av = load4(dec, isbf, (long)(m0 + lrow) * ND + (kt - NE) + lk4);
        }
        float4 bv = load4(Wfin, isbf, (long)(kt + lkb) * ND + n0 + ln4);
        As[lk4 + 0][lrow] = av.x; As[lk4 + 1][lrow] = av.y;
        As[lk4 + 2][lrow] = av.z; As[lk4 + 3][lrow] = av.w;
        *(float4*)&Bs[lkb][ln4] = bv;
        __syncthreads();
#pragma unroll
        for (int k = 0; k < 16; ++k) {
            float4 a = *(const float4*)&As[k][ty << 2];
            float4 b = *(const float4*)&Bs[k][tx << 2];
            acc[0][0] = fmaf(a.x, b.x, acc[0][0]); acc[0][1] = fmaf(a.x, b.y, acc[0][1]);
            acc[0][2] = fmaf(a.x, b.z, acc[0][2]); acc[0][3] = fmaf(a.x, b.w, acc[0][3]);
            acc[1][0] = fmaf(a.y, b.x, acc[1][0]); acc[1][1] = fmaf(a.y, b.y, acc[1][1]);
            acc[1][2] = fmaf(a.y, b.z, acc[1][2]); acc[1][3] = fmaf(a.y, b.w, acc[1][3]);
            acc[2][0] = fmaf(a.z, b.x, acc[2][0]); acc[2][1] = fmaf(a.z, b.y, acc[2][1]);
            acc[2][2] = fmaf(a.z, b.z, acc[2][2]); acc[2][3] = fmaf(a.z, b.w, acc[2][3]);
            acc[3][0] = fmaf(a.w, b.x, acc[3][0]); acc[3][1] = fmaf(a.w, b.y, acc[3][1]);
            acc[3][2] = fmaf(a.w, b.z, acc[3][2]); acc[3][3] = fmaf(a.w, b.w, acc[3][3]);
        }
        __syncthreads();
    }
    if (isbf) {
        unsigned short* o = (unsigned short*)out;
#pragma unroll
        for (int i = 0; i < 4; ++i) {
            long base = (long)(m0 + (ty << 2) + i) * ND + n0 + (tx << 2);
            ushort4 r;
            r.x = f2bf(tanhf(acc[i][0])); r.y = f2bf(tanhf(acc[i][1]));
            r.z = f2bf(tanhf(acc[i][2])); r.w = f2bf(tanhf(acc[i][3]));
            *(ushort4*)&o[base] = r;
        }
    } else {
        float* o = (float*)out;
#pragma unroll
        for (int i = 0; i < 4; ++i) {
            long base = (long)(m0 + (ty << 2) + i) * ND + n0 + (tx << 2);
            float4 r = make_float4(tanhf(acc[i][0]), tanhf(acc[i][1]),
                                   tanhf(acc[i][2]), tanhf(acc[i][3]));
            *(float4*)&o[base] = r;
        }
    }
}

extern "C" void kernel_launch(void* const* d_in, const int* in_sizes, int n_in,
                              void* d_out, int out_size, void* d_ws, size_t ws_size,
                              hipStream_t stream) {
    const void* enc  = d_in[0];  // (B,S,E)
    const void* dec  = d_in[1];  // (B,T,D)
    const void* mask = d_in[2];  // (B,S) bool
    const void* Wenc = d_in[3];  // (E,D)
    const void* Wfin = d_in[4];  // (E+D,D)

    unsigned short* ehb = (unsigned short*)d_ws;              // 16.8 MB
    unsigned short* elb = ehb + (size_t)NB * NS * NE;         // 16.8 MB
    unsigned short* qhb = elb + (size_t)NB * NS * NE;         // 8.4 MB
    unsigned short* qlb = qhb + (size_t)NM * NE;              // 8.4 MB
    const size_t fixed = ((size_t)NB * NS * NE * 2 + (size_t)NM * NE * 2) * 2;  // bytes

    // pick s-split factor by available workspace (partial ctx + M/L per part)
    int parts = 1;
    for (int p = 4; p >= 1; p >>= 1) {
        size_t need = fixed + (size_t)p * NM * NE * 4 + (size_t)p * NM * 8 + 256;
        if (ws_size >= need) { parts = p; break; }
    }
    float* ctx  = (float*)(qlb + (size_t)NM * NE);            // parts x 16.8 MB
    float* Mpb  = ctx + (size_t)parts * NM * NE;
    float* Lpb  = Mpb + (size_t)parts * NM;
    int*   flags = (int*)(Lpb + (size_t)parts * NM);

    k_detect<<<1, 256, 0, stream>>>(enc, mask, flags);
    k_split_e<<<(NB * NS * NE) / (256 * 8), 256, 0, stream>>>(enc, flags, ehb, elb);
    k_q<<<dim3(NM / 64, NE / 64), 256, 0, stream>>>(dec, Wenc, flags, qhb, qlb);
    k_attn<<<dim3(NT / 32, NB, parts), 256, 0, stream>>>(qhb, qlb, ehb, elb, mask, flags,
                                                         ctx, Mpb, Lpb);
    if (parts > 1)
        k_comb<<<NM / 8, 256, 0, stream>>>(ctx, Mpb, Lpb, parts);
    k_final<<<dim3(NM / 64, ND / 64), 256, 0, stream>>>(ctx, dec, Wfin, flags, d_out);
}